// Round 4
// baseline (557.763 us; speedup 1.0000x reference)
//
#include <hip/hip_runtime.h>

// Problem constants (z: [4, 64, 32, 32, 32] f32, embedding: [1024, 64] f32)
#define CH     64
#define KC     1024
#define SP     32768              // 32*32*32
#define NBATCH 4
#define NTOK   (NBATCH * SP)      // 131072

// d_out flat layout (all float32): z_q, loss, perplexity, indices, mean(dist)
#define OFF_ZQ   0
#define OFF_LOSS (NBATCH * CH * SP)      // 8388608
#define OFF_PERP (OFF_LOSS + 1)
#define OFF_IDX  (OFF_PERP + 1)          // 8388610
#define OFF_MEAN (OFF_IDX + NTOK)        // 8519682

// workspace layout (32-bit words)
// [0,1024)      int   hist
// [1024]        float sum_z2
// [1025]        float sum_e2
// [1026,1090)   float sum_zc[64]
// [1090,1154)   float sum_ec[64]
// [1154,2178)   float enorm[1024]

// Fused prep: blocks 0-3 embed_norms, block 4 embed_col_stats (+ zero the
// atomic targets sums[0]/sum_zc), blocks 5-8 zero hist.
__global__ __launch_bounds__(256) void prep(const float* __restrict__ e,
                                            int* __restrict__ hist,
                                            float* __restrict__ sums,
                                            float* __restrict__ sum_zc,
                                            float* __restrict__ sum_ec,
                                            float* __restrict__ enorm) {
    const int tid = threadIdx.x;
    const int bk = blockIdx.x;
    if (bk < 4) {
        // ||e_k||^2 for each code
        int k = bk * 256 + tid;
        const float4* row = (const float4*)(e + (size_t)k * CH);
        float n = 0.f;
#pragma unroll
        for (int j = 0; j < CH / 4; ++j) {
            float4 v = row[j];
            n += v.x * v.x + v.y * v.y + v.z * v.z + v.w * v.w;
        }
        enorm[k] = n;
    } else if (bk == 4) {
        // zero z_stats' atomic targets (disjoint from this block's outputs)
        if (tid == 0) sums[0] = 0.f;
        if (tid < 64) sum_zc[tid] = 0.f;
        // per-channel sums of embedding + total sum of squares
        __shared__ float ls1[256];
        __shared__ float r2[4];
        int c = tid & 63;
        int strip = tid >> 6;
        float s1 = 0.f, s2 = 0.f;
        for (int k = strip * 256; k < strip * 256 + 256; ++k) {
            float v = e[k * CH + c];
            s1 += v;
            s2 = fmaf(v, v, s2);
        }
        ls1[tid] = s1;
        for (int off = 32; off; off >>= 1) s2 += __shfl_down(s2, off);
        if ((tid & 63) == 0) r2[tid >> 6] = s2;
        __syncthreads();
        if (strip == 0) sum_ec[c] = ls1[c] + ls1[64 + c] + ls1[128 + c] + ls1[192 + c];
        if (tid == 0) sums[1] = r2[0] + r2[1] + r2[2] + r2[3];
    } else {
        hist[(bk - 5) * 256 + tid] = 0;
    }
}

// sum z^2 (scalar) and per-channel sum of z.
__global__ __launch_bounds__(256) void z_stats(const float* __restrict__ z,
                                               float* __restrict__ sums,
                                               float* __restrict__ sum_zc) {
    const int tid = threadIdx.x;
    const size_t base = (size_t)blockIdx.x * 4096;
    float s1 = 0.f, s2 = 0.f;
#pragma unroll
    for (int j = 0; j < 4; ++j) {
        float4 v = *(const float4*)(z + base + (size_t)tid * 4 + (size_t)j * 1024);
        s1 += v.x + v.y + v.z + v.w;
        s2 += v.x * v.x + v.y * v.y + v.z * v.z + v.w * v.w;
    }
    for (int off = 32; off; off >>= 1) {
        s1 += __shfl_down(s1, off);
        s2 += __shfl_down(s2, off);
    }
    __shared__ float r1[4], r2[4];
    int w = tid >> 6, ln = tid & 63;
    if (ln == 0) { r1[w] = s1; r2[w] = s2; }
    __syncthreads();
    if (tid == 0) {
        float t1 = r1[0] + r1[1] + r1[2] + r1[3];
        float t2 = r2[0] + r2[1] + r2[2] + r2[3];
        int c = (int)((base >> 15) & 63);
        atomicAdd(&sum_zc[c], t1);
        atomicAdd(&sums[0], t2);
    }
}

// main: lane = token. z[64] lives in VGPRs; the e-row index is wave-uniform,
// so e loads become s_load (SMEM pipe) and each v_fma takes e as its single
// SGPR operand. Zero LDS in the hot loop — the round-3 wall (LDS b128
// throughput) is gone. Arithmetic is bitwise-identical to rounds 1/3:
// stride-4 fmaf chains ascending in c, combine nrm - 2*((a0+a1)+(a2+a3)),
// sequential strict-< argmin over ascending code (= first-min).
__global__ __launch_bounds__(256, 4) void vq_main(const float* __restrict__ z,
                                                  const float* __restrict__ emb,
                                                  const float* __restrict__ enorm,
                                                  float* __restrict__ out,
                                                  int* __restrict__ hist) {
    __shared__ int lh[KC];   // 4 KB block histogram

    const int tid = threadIdx.x;
    const int t = blockIdx.x * 256 + tid;   // token id, grid = 512
    const int b = t >> 15;
    const int s = t & (SP - 1);

    for (int i = tid; i < KC; i += 256) lh[i] = 0;

    const float* zp = z + (size_t)b * (CH * SP) + s;
    float zr[CH];
#pragma unroll
    for (int c = 0; c < CH; ++c) zr[c] = zp[(size_t)c * SP];   // coalesced per c

    float bestv = 3.4e38f;
    int besti = 0;

    for (int code = 0; code < KC; ++code) {
        const float4* er = (const float4*)(emb + (size_t)code * CH);  // uniform
        float a0 = 0.f, a1 = 0.f, a2 = 0.f, a3 = 0.f;
#pragma unroll
        for (int j = 0; j < 16; ++j) {
            float4 e4 = er[j];              // wave-uniform -> s_load_dwordx4
            a0 = fmaf(zr[4 * j + 0], e4.x, a0);
            a1 = fmaf(zr[4 * j + 1], e4.y, a1);
            a2 = fmaf(zr[4 * j + 2], e4.z, a2);
            a3 = fmaf(zr[4 * j + 3], e4.w, a3);
        }
        // EXACT rounds-1/3 expression tree
        float d = enorm[code] - 2.f * ((a0 + a1) + (a2 + a3));
        if (d < bestv) { bestv = d; besti = code; }
    }

    // indices output (buffer is float32), coalesced
    out[OFF_IDX + t] = (float)besti;

    // histogram: LDS then one global atomic per nonzero bin
    atomicAdd(&lh[besti], 1);
    __syncthreads();
    for (int i = tid; i < KC; i += 256) {
        int v = lh[i];
        if (v) atomicAdd(&hist[i], v);
    }

    // z_q = z + (e[besti] - z): per-lane gather from the L2-hot 256 KB table,
    // writes coalesced per channel. Identical to the passing round-1 epilogue.
    const float4* eq = (const float4*)(emb + (size_t)besti * CH);
    float* oq = out + OFF_ZQ + (size_t)b * (CH * SP) + s;
#pragma unroll
    for (int j = 0; j < CH / 4; ++j) {
        float4 v = eq[j];
        int c = 4 * j;
        oq[(size_t)(c + 0) * SP] = zr[c + 0] + (v.x - zr[c + 0]);
        oq[(size_t)(c + 1) * SP] = zr[c + 1] + (v.y - zr[c + 1]);
        oq[(size_t)(c + 2) * SP] = zr[c + 2] + (v.z - zr[c + 2]);
        oq[(size_t)(c + 3) * SP] = zr[c + 3] + (v.w - zr[c + 3]);
    }
}

__global__ __launch_bounds__(1024) void finalize(const int* __restrict__ hist,
                                                 const float* __restrict__ sums,
                                                 const float* __restrict__ sum_zc,
                                                 const float* __restrict__ sum_ec,
                                                 float* __restrict__ out) {
    __shared__ float red[1024];
    int k = threadIdx.x;
    float p = (float)hist[k] * (1.0f / (float)NTOK);
    red[k] = p * logf(p + 1e-10f);
    __syncthreads();
    for (int off = 512; off; off >>= 1) {
        if (k < off) red[k] += red[k + off];
        __syncthreads();
    }
    if (k == 0) {
        out[OFF_PERP] = expf(-red[0]);
        out[OFF_LOSS] = 0.f;
        double dot = 0.0;
        for (int c = 0; c < CH; ++c) dot += (double)sum_zc[c] * (double)sum_ec[c];
        double mean = ((double)KC * (double)sums[0] + (double)NTOK * (double)sums[1] - 2.0 * dot)
                      / ((double)NTOK * (double)KC);
        out[OFF_MEAN] = (float)mean;
    }
}

extern "C" void kernel_launch(void* const* d_in, const int* in_sizes, int n_in,
                              void* d_out, int out_size, void* d_ws, size_t ws_size,
                              hipStream_t stream) {
    const float* z   = (const float*)d_in[0];
    const float* emb = (const float*)d_in[1];
    float* out = (float*)d_out;

    int*   hist   = (int*)d_ws;
    float* sums   = (float*)d_ws + 1024;   // [0]=sum_z2 [1]=sum_e2
    float* sum_zc = (float*)d_ws + 1026;
    float* sum_ec = (float*)d_ws + 1090;
    float* enorm  = (float*)d_ws + 1154;

    prep<<<9, 256, 0, stream>>>(emb, hist, sums, sum_zc, sum_ec, enorm);
    z_stats<<<(NBATCH * CH * SP) / 4096, 256, 0, stream>>>(z, sums, sum_zc);
    vq_main<<<NTOK / 256, 256, 0, stream>>>(z, emb, enorm, out, hist);
    finalize<<<1, 1024, 0, stream>>>(hist, sums, sum_zc, sum_ec, out);
}